// Round 13
// baseline (53.872 us; speedup 1.0000x reference)
//
#include <hip/hip_runtime.h>

#define NUM_CODE 2048
#define DIM_CODE 512

typedef float f32x4 __attribute__((ext_vector_type(4)));

// One WAVE (64 lanes) per row, 4 independent waves per block, zero LDS /
// zero barriers (R9 structure). Definitive MLP probe: ONE volatile asm pins
// ALL 16 float4s (x and noise) after the load region -- every load must
// complete before it, no load can be sunk past it, 64 data VGPRs provably
// live at once (validity gate: VGPR_Count ~80-90, vs 36/44 when the
// compiler defeated R10/R11's partial pins).
// Arithmetic identical to R9-R11: no max-sub, __expf, single rcp, nt stores.
__global__ __launch_bounds__(256) void vq_row_kernel(
    const float* __restrict__ x,
    const float* __restrict__ noise,
    const float* __restrict__ codebook,
    float* __restrict__ out)
{
    const int tid  = threadIdx.x;
    const int lane = tid & 63;
    const int wave = tid >> 6;
    const int row  = blockIdx.x * 4 + wave;

    const f32x4* x4 = (const f32x4*)(x     + (size_t)row * NUM_CODE);
    const f32x4* n4 = (const f32x4*)(noise + (size_t)row * NUM_CODE);

    // lane l, chunk j -> float4 index j*64+l -> elements 256j + 4l .. +3
    f32x4 a[8];   // x, overwritten by e = exp(x)
    f32x4 nz[8];  // noise, pinned in registers until argmax
    #pragma unroll
    for (int j = 0; j < 8; ++j) a[j]  = x4[j * 64 + lane];
    #pragma unroll
    for (int j = 0; j < 8; ++j) nz[j] = n4[j * 64 + lane];

    // single pin covering ALL loaded data: nothing may sink past this point
    asm volatile("" : "+v"(a[0]),  "+v"(a[1]),  "+v"(a[2]),  "+v"(a[3]),
                      "+v"(a[4]),  "+v"(a[5]),  "+v"(a[6]),  "+v"(a[7]),
                      "+v"(nz[0]), "+v"(nz[1]), "+v"(nz[2]), "+v"(nz[3]),
                      "+v"(nz[4]), "+v"(nz[5]), "+v"(nz[6]), "+v"(nz[7]));
    __builtin_amdgcn_sched_barrier(0);

    // ---- exp (no max-sub) + row sum; e overwrites x in place ----
    float s = 0.f;
    #pragma unroll
    for (int j = 0; j < 8; ++j) {
        a[j].x = __expf(a[j].x);
        a[j].y = __expf(a[j].y);
        a[j].z = __expf(a[j].z);
        a[j].w = __expf(a[j].w);
        s += (a[j].x + a[j].y) + (a[j].z + a[j].w);
    }
    #pragma unroll
    for (int off = 32; off; off >>= 1)
        s += __shfl_xor(s, off);
    const float inv = 1.0f / s;  // single division

    // ---- argmax(sm - noise), first-index tie-break ----
    float bv = -INFINITY; int bi = 0;
    #pragma unroll
    for (int j = 0; j < 8; ++j) {
        const int base = 256 * j + 4 * lane;
        { float v = a[j].x * inv - nz[j].x; if (v > bv) { bv = v; bi = base;     } }
        { float v = a[j].y * inv - nz[j].y; if (v > bv) { bv = v; bi = base + 1; } }
        { float v = a[j].z * inv - nz[j].z; if (v > bv) { bv = v; bi = base + 2; } }
        { float v = a[j].w * inv - nz[j].w; if (v > bv) { bv = v; bi = base + 3; } }
    }
    #pragma unroll
    for (int off = 32; off; off >>= 1) {
        float ov = __shfl_xor(bv, off);
        int   oi = __shfl_xor(bi, off);
        if (ov > bv || (ov == bv && oi < bi)) { bv = ov; bi = oi; }
    }

    // ---- gather codebook[bi] -> out[row]: 64 lanes x 2 float4, nt stores ----
    const f32x4* cb = (const f32x4*)(codebook + (size_t)bi * DIM_CODE);
    float* o = out + (size_t)row * DIM_CODE;
    const f32x4 c0 = cb[lane];
    const f32x4 c1 = cb[64 + lane];
    float* p0 = o + 4 * lane;
    float* p1 = o + 256 + 4 * lane;
    __builtin_nontemporal_store(c0.x, p0);
    __builtin_nontemporal_store(c0.y, p0 + 1);
    __builtin_nontemporal_store(c0.z, p0 + 2);
    __builtin_nontemporal_store(c0.w, p0 + 3);
    __builtin_nontemporal_store(c1.x, p1);
    __builtin_nontemporal_store(c1.y, p1 + 1);
    __builtin_nontemporal_store(c1.z, p1 + 2);
    __builtin_nontemporal_store(c1.w, p1 + 3);
}

extern "C" void kernel_launch(void* const* d_in, const int* in_sizes, int n_in,
                              void* d_out, int out_size, void* d_ws, size_t ws_size,
                              hipStream_t stream) {
    const float* x        = (const float*)d_in[0];
    const float* noise    = (const float*)d_in[1];
    const float* codebook = (const float*)d_in[2];
    float* out            = (float*)d_out;

    const int n_rows = in_sizes[0] / NUM_CODE;  // 16384
    vq_row_kernel<<<n_rows / 4, 256, 0, stream>>>(x, noise, codebook, out);
}

// Round 14
// 53.567 us; speedup vs baseline: 1.0057x; 1.0057x over previous
//
#include <hip/hip_runtime.h>

#define NUM_CODE 2048
#define DIM_CODE 512

typedef float f32x4 __attribute__((ext_vector_type(4)));

// One WAVE per row, 4 waves/block. Concurrency fix the compiler cannot
// defeat: noise is fetched with __builtin_amdgcn_global_load_lds (side-
// effecting intrinsic -- cannot be sunk or RA-rematerialized like the
// register loads were in R10/R11/R13), pinned by sched_barrier(0), so all
// 16 memory requests (8x x->VGPR + 8x noise->LDS) are in flight while the
// exp/sum chain runs. Wave-private LDS region -> no __syncthreads; the
// vmcnt(0) wait covers the LDS fill.
// Arithmetic identical to R9-R13: no max-sub, __expf, single rcp, nt stores.
__global__ __launch_bounds__(256) void vq_row_kernel(
    const float* __restrict__ x,
    const float* __restrict__ noise,
    const float* __restrict__ codebook,
    float* __restrict__ out)
{
    __shared__ float lds_nz[4][NUM_CODE];   // 32 KB/block, 8 KB per wave

    const int tid  = threadIdx.x;
    const int lane = tid & 63;
    const int wave = tid >> 6;
    const int row  = blockIdx.x * 4 + wave;

    const f32x4* x4   = (const f32x4*)(x + (size_t)row * NUM_CODE);
    const float* nrow = noise + (size_t)row * NUM_CODE;

    // ---- x into registers: 8 x 16B per lane in flight ----
    f32x4 a[8];
    #pragma unroll
    for (int j = 0; j < 8; ++j) a[j] = x4[j * 64 + lane];

    // ---- noise into LDS via direct-to-LDS DMA, issued behind the x loads.
    // dest = wave-uniform base + lane*16B; call j fills floats 256j..256j+255
    // of this wave's row (lane l -> elements 256j + 4l .. +3, matching the
    // register-path layout exactly).
    #pragma unroll
    for (int j = 0; j < 8; ++j) {
        __builtin_amdgcn_global_load_lds(
            (const __attribute__((address_space(1))) void*)(nrow + 256 * j + 4 * lane),
            (__attribute__((address_space(3))) void*)&lds_nz[wave][256 * j],
            16, 0, 0);
    }
    __builtin_amdgcn_sched_barrier(0);   // loads may not sink below this point

    // ---- exp (no max-sub) + row sum while noise streams into LDS ----
    float s = 0.f;
    #pragma unroll
    for (int j = 0; j < 8; ++j) {
        a[j].x = __expf(a[j].x);
        a[j].y = __expf(a[j].y);
        a[j].z = __expf(a[j].z);
        a[j].w = __expf(a[j].w);
        s += (a[j].x + a[j].y) + (a[j].z + a[j].w);
    }
    #pragma unroll
    for (int off = 32; off; off >>= 1)
        s += __shfl_xor(s, off);
    const float inv = 1.0f / s;  // single division

    // ---- wait for the LDS fill (wave-private: no barrier needed) ----
    asm volatile("s_waitcnt vmcnt(0)" ::: "memory");
    __builtin_amdgcn_sched_barrier(0);

    // ---- argmax(sm - noise) from LDS, first-index tie-break ----
    float bv = -INFINITY; int bi = 0;
    #pragma unroll
    for (int j = 0; j < 8; ++j) {
        const f32x4 nz = *(const f32x4*)&lds_nz[wave][256 * j + 4 * lane];
        const int base = 256 * j + 4 * lane;
        { float v = a[j].x * inv - nz.x; if (v > bv) { bv = v; bi = base;     } }
        { float v = a[j].y * inv - nz.y; if (v > bv) { bv = v; bi = base + 1; } }
        { float v = a[j].z * inv - nz.z; if (v > bv) { bv = v; bi = base + 2; } }
        { float v = a[j].w * inv - nz.w; if (v > bv) { bv = v; bi = base + 3; } }
    }
    #pragma unroll
    for (int off = 32; off; off >>= 1) {
        float ov = __shfl_xor(bv, off);
        int   oi = __shfl_xor(bi, off);
        if (ov > bv || (ov == bv && oi < bi)) { bv = ov; bi = oi; }
    }

    // ---- gather codebook[bi] -> out[row]: 64 lanes x 2 float4, nt stores ----
    const f32x4* cb = (const f32x4*)(codebook + (size_t)bi * DIM_CODE);
    float* o = out + (size_t)row * DIM_CODE;
    const f32x4 c0 = cb[lane];
    const f32x4 c1 = cb[64 + lane];
    float* p0 = o + 4 * lane;
    float* p1 = o + 256 + 4 * lane;
    __builtin_nontemporal_store(c0.x, p0);
    __builtin_nontemporal_store(c0.y, p0 + 1);
    __builtin_nontemporal_store(c0.z, p0 + 2);
    __builtin_nontemporal_store(c0.w, p0 + 3);
    __builtin_nontemporal_store(c1.x, p1);
    __builtin_nontemporal_store(c1.y, p1 + 1);
    __builtin_nontemporal_store(c1.z, p1 + 2);
    __builtin_nontemporal_store(c1.w, p1 + 3);
}

extern "C" void kernel_launch(void* const* d_in, const int* in_sizes, int n_in,
                              void* d_out, int out_size, void* d_ws, size_t ws_size,
                              hipStream_t stream) {
    const float* x        = (const float*)d_in[0];
    const float* noise    = (const float*)d_in[1];
    const float* codebook = (const float*)d_in[2];
    float* out            = (float*)d_out;

    const int n_rows = in_sizes[0] / NUM_CODE;  // 16384
    vq_row_kernel<<<n_rows / 4, 256, 0, stream>>>(x, noise, codebook, out);
}